// Round 11
// baseline (222.371 us; speedup 1.0000x reference)
//
#include <hip/hip_runtime.h>
#include <hip/hip_bf16.h>
#include <stdint.h>
#include <math.h>

typedef unsigned short ushort_t;
typedef __attribute__((ext_vector_type(4))) float f32x4;
typedef __attribute__((ext_vector_type(16))) float f32x16;
typedef __attribute__((ext_vector_type(8))) __bf16 bf16x8;
typedef __attribute__((ext_vector_type(8))) unsigned short ushort8;
typedef __attribute__((ext_vector_type(4))) unsigned short ushort4v;

__device__ __forceinline__ float bf2f(ushort_t u) {
  union { unsigned u32; float f; } x; x.u32 = ((unsigned)u) << 16; return x.f;
}
__device__ __forceinline__ ushort_t f2bf(float f) {
  union { float f; unsigned u; } x; x.f = f;
  unsigned r = x.u + 0x7FFF + ((x.u >> 16) & 1);
  return (ushort_t)(r >> 16);
}

// async global->LDS, 16 bytes per lane (global_load_lds_dwordx4)
__device__ __forceinline__ void gld16(const ushort_t* g, ushort_t* l) {
  __builtin_amdgcn_global_load_lds(
      (const __attribute__((address_space(1))) uint32_t*)g,
      (__attribute__((address_space(3))) uint32_t*)l, 16, 0, 0);
}

// ------- merged cast fp32->bf16 (x,Wq,Wk,Wv) + rowsum zero (4 blocks) ------
__global__ __launch_bounds__(256) void cast_all_kernel(
    const float* __restrict__ x, const float* __restrict__ wq,
    const float* __restrict__ wk, const float* __restrict__ wv,
    ushort_t* __restrict__ xb, ushort_t* __restrict__ wqb,
    ushort_t* __restrict__ wkb, ushort_t* __restrict__ wvb,
    float* __restrict__ rowsum) {
  int blk = blockIdx.x;
  if (blk >= 4096 + 1536) {  // rowsum zero: 4 blocks x 256 thr x 8 floats
    int idx = (blk - (4096 + 1536)) * 256 + threadIdx.x;  // 0..1023
    f32x4 z = {0.f, 0.f, 0.f, 0.f};
    ((f32x4*)rowsum)[idx * 2] = z;
    ((f32x4*)rowsum)[idx * 2 + 1] = z;
    return;
  }
  const float* in;
  ushort_t* out;
  int i;
  if (blk < 4096) {               // x: 8388608 elems = 4096 blocks
    in = x; out = xb; i = blk * 256 + threadIdx.x;
  } else {
    int w = (blk - 4096) >> 9;    // 512 blocks per weight matrix
    int lb = (blk - 4096) & 511;
    in = (w == 0) ? wq : (w == 1) ? wk : wv;
    out = (w == 0) ? wqb : (w == 1) ? wkb : wvb;
    i = lb * 256 + threadIdx.x;
  }
  const f32x4* p = (const f32x4*)in;
  f32x4 a = p[2 * i];
  f32x4 b = p[2 * i + 1];
  ushort8 o;
  o[0] = f2bf(a[0]); o[1] = f2bf(a[1]); o[2] = f2bf(a[2]); o[3] = f2bf(a[3]);
  o[4] = f2bf(b[0]); o[5] = f2bf(b[1]); o[6] = f2bf(b[2]); o[7] = f2bf(b[3]);
  *((ushort8*)out + i) = o;
}

// ---------------- PROVEN 128x128 core, now on 32x32x16 MFMA ---------------
// Same staging / XOR-swizzle / __syncthreads structure as the 903 TF core
// (R10, measured-settled). Only the MFMA shape changed: 32x32x16 bf16 runs
// ~15-18% faster per FLOP than 16x16x32 (m119: 2495 vs ~2176 TF ubench).
// Per wave per K-tile: 16 MFMA + 16 ds_read_b128 (was 32 + 16); frag regs
// halve (af/bf 2+2 vs 4+4). A/B layout: row|col = lane&31, k = (lane>>5)*8+i
// (same verified family as the 16x16 layout in use since R0). Reader
// un-swizzle: row&7 = lane&7 -> chunk = (c*2 + (lane>>5)) ^ (lane&7).
#define BM 128
#define BN 128
#define BK 64

__device__ __forceinline__ void gemm_core(
    const ushort_t* __restrict__ A, const ushort_t* __restrict__ B, int Kd,
    int kEnd, int m0, int n0, ushort_t* As, ushort_t* Bs, f32x16 (&acc)[2][2]) {
  int tid = threadIdx.x;
  int lane = tid & 63;
  int wave = tid >> 6;
  int wr = (wave >> 1) * 64;
  int wc = (wave & 1) * 64;
  int l31 = lane & 31;
  int lh = lane >> 5;           // 0/1: k-half within the K=16 window
  int xr = lane & 7;            // row&7 un-swizzle key (row = ...+l31)

  int row = tid >> 3;                              // 0..31 (base row of chunk)
  int ksw = ((tid & 7) ^ (row & 7)) * 8;           // swizzled k-offset (elems)
  const ushort_t* aB = A + (size_t)(m0 + row) * Kd + ksw;
  const ushort_t* bB = B + (size_t)(n0 + row) * Kd + ksw;

  for (int k0 = 0; k0 < kEnd; k0 += BK) {
    __syncthreads();
#pragma unroll
    for (int r = 0; r < 4; ++r) {
      gld16(aB + (size_t)(32 * r) * Kd + k0, &As[(tid + 256 * r) * 8]);
      gld16(bB + (size_t)(32 * r) * Kd + k0, &Bs[(tid + 256 * r) * 8]);
    }
    __syncthreads();
#pragma unroll
    for (int c = 0; c < 4; ++c) {  // 4 k-windows of 16
      bf16x8 af[2], bfr[2];
#pragma unroll
      for (int fi = 0; fi < 2; ++fi)
        af[fi] = *(const bf16x8*)
            &As[(wr + fi * 32 + l31) * BK + (((c * 2 + lh) ^ xr) * 8)];
#pragma unroll
      for (int fj = 0; fj < 2; ++fj)
        bfr[fj] = *(const bf16x8*)
            &Bs[(wc + fj * 32 + l31) * BK + (((c * 2 + lh) ^ xr) * 8)];
#pragma unroll
      for (int fi = 0; fi < 2; ++fi)
#pragma unroll
        for (int fj = 0; fj < 2; ++fj)
          acc[fi][fj] = __builtin_amdgcn_mfma_f32_32x32x16_bf16(
              af[fi], bfr[fj], acc[fi][fj], 0, 0, 0);
    }
  }
}

// C/D layout for 32x32 (HW-verified m74/m101):
//   col = lane&31, row = (reg&3) + 8*(reg>>2) + 4*(lane>>5), reg in [0,16)

// QKV projection, PLAIN (64,8,3) grid (measured-best three times; R9 pin
// regressed). 1536 blocks = exactly 2 residency rounds. V (z==2) writes
// transposed with the proven scatter (regs 4g..4g+3 = 4 consecutive tokens).
__global__ __launch_bounds__(256, 3) void gemm_qkv(
    const ushort_t* __restrict__ xb, const ushort_t* __restrict__ wq,
    const ushort_t* __restrict__ wk, const ushort_t* __restrict__ wv,
    ushort_t* __restrict__ Qb, ushort_t* __restrict__ Kb,
    ushort_t* __restrict__ Vt) {
  int m0 = blockIdx.x * BM, n0 = blockIdx.y * BN;
  int z = blockIdx.z;
  const ushort_t* B = (z == 0) ? wq : (z == 1) ? wk : wv;

  __shared__ ushort_t As[BM * BK];
  __shared__ ushort_t Bs[BN * BK];

  f32x16 acc[2][2];
#pragma unroll
  for (int i = 0; i < 2; ++i)
#pragma unroll
    for (int j = 0; j < 2; ++j)
#pragma unroll
      for (int r = 0; r < 16; ++r) acc[i][j][r] = 0.f;

  gemm_core(xb, B, 1024, 1024, m0, n0, As, Bs, acc);

  int tid = threadIdx.x;
  int lane = tid & 63;
  int wave = tid >> 6;
  int wr = (wave >> 1) * 64;
  int wc = (wave & 1) * 64;
  int l31 = lane & 31;
  int lh = lane >> 5;

  if (z < 2) {
    ushort_t* C = (z == 0) ? Qb : Kb;
#pragma unroll
    for (int fi = 0; fi < 2; ++fi)
#pragma unroll
      for (int fj = 0; fj < 2; ++fj)
#pragma unroll
        for (int r = 0; r < 16; ++r) {
          int rrow = m0 + wr + fi * 32 + (r & 3) + 8 * (r >> 2) + 4 * lh;
          int col = n0 + wc + fj * 32 + l31;
          C[(size_t)rrow * 1024 + col] = f2bf(acc[fi][fj][r]);
        }
  } else {
    // V transposed: Vt[b][d][n]; regs 4g..4g+3 are tokens gm..gm+3
#pragma unroll
    for (int fi = 0; fi < 2; ++fi)
#pragma unroll
      for (int fj = 0; fj < 2; ++fj)
#pragma unroll
        for (int g = 0; g < 4; ++g) {
          int gm = m0 + wr + fi * 32 + 8 * g + 4 * lh;
          int b = gm >> 11, nn = gm & 2047;
          int d = n0 + wc + fj * 32 + l31;
          ushort4v v;
#pragma unroll
          for (int q = 0; q < 4; ++q) v[q] = f2bf(acc[fi][fj][4 * g + q]);
          *(ushort4v*)&Vt[(size_t)b * (2048 * 1024) + (size_t)d * 2048 + nn] =
              v;
        }
  }
}

// S-GEMM, XCD-pinned by batch pair, single dispatch round (544 = 8 x 68,
// R10 measured-good). Rowsum reduce: 32-lane shfl_xor (1..16) stays within
// each half-wave; halves own different rows (4*lh term) -> one atomic per
// half per (fi, reg).
__global__ __launch_bounds__(256, 3) void gemm_s(
    const ushort_t* __restrict__ Qg, const ushort_t* __restrict__ Kg,
    ushort_t* __restrict__ Eg, float scale, float* __restrict__ rowsum) {
  int L = blockIdx.x;
  int xcd = L & 7;
  int slot = L >> 3;                        // 0..67
  int bz = xcd >> 1;
  int t = ((xcd & 1) * 68) + slot;          // 0..135 triangular index
  int m = (int)((sqrtf(8.f * (float)t + 1.f) - 1.f) * 0.5f);
  while ((m + 1) * (m + 2) / 2 <= t) ++m;   // guard float edge cases
  while (m * (m + 1) / 2 > t) --m;
  int n = t - m * (m + 1) / 2;              // 0..m
  int m0 = m * BM, n0 = n * BN;
  const ushort_t* A = Qg + (size_t)bz * (2048 * 1024);
  const ushort_t* B = Kg + (size_t)bz * (2048 * 1024);

  __shared__ ushort_t As[BM * BK];
  __shared__ ushort_t Bs[BN * BK];

  f32x16 acc[2][2];
#pragma unroll
  for (int i = 0; i < 2; ++i)
#pragma unroll
    for (int j = 0; j < 2; ++j)
#pragma unroll
      for (int r = 0; r < 16; ++r) acc[i][j][r] = 0.f;

  gemm_core(A, B, 1024, 1024, m0, n0, As, Bs, acc);

  int tid = threadIdx.x;
  int lane = tid & 63;
  int wave = tid >> 6;
  int wr = (wave >> 1) * 64;
  int wc = (wave & 1) * 64;
  int l31 = lane & 31;
  int lh = lane >> 5;

  // S epilogue: exp (no max-sub; |s*scale| < ~2.5) + bf16 E + rowsum
  ushort_t* C = Eg + (size_t)bz * (2048 * 2048);
  float* rs = rowsum + (size_t)bz * 2048;
#pragma unroll
  for (int fi = 0; fi < 2; ++fi)
#pragma unroll
    for (int r = 0; r < 16; ++r) {
      int grow = m0 + wr + fi * 32 + (r & 3) + 8 * (r >> 2) + 4 * lh;
      float psum = 0.f;
#pragma unroll
      for (int fj = 0; fj < 2; ++fj) {
        int col = n0 + wc + fj * 32 + l31;
        float e = (col <= grow) ? __expf(acc[fi][fj][r] * scale) : 0.f;
        C[(size_t)grow * 2048 + col] = f2bf(e);
        psum += e;
      }
      psum += __shfl_xor(psum, 1);
      psum += __shfl_xor(psum, 2);
      psum += __shfl_xor(psum, 4);
      psum += __shfl_xor(psum, 8);
      psum += __shfl_xor(psum, 16);
      if (l31 == 0) atomicAdd(&rs[grow], psum);
    }
}

// O-GEMM, XCD-PINNED (R10 verbatim map): flat 512 = 8 x 64, batch = xcd>>1.
// m = mm even ? 15-mm/2 : (mm-1)/2 -> longest-K first, equal total K per
// XCD half. E and rowsum are L2-warm from gemm_s (same pair).
__global__ __launch_bounds__(256, 3) void gemm_o(
    const ushort_t* __restrict__ Eg, const ushort_t* __restrict__ Vg,
    float* __restrict__ Og, const float* __restrict__ rowsum) {
  int L = blockIdx.x;
  int xcd = L & 7;
  int slot = L >> 3;                        // 0..63
  int bz = xcd >> 1;
  int idx = ((xcd & 1) * 64) + slot;        // 0..127
  int n = idx & 7;
  int mm = idx >> 3;                        // 0..15
  int m = (mm & 1) ? (mm >> 1) : (15 - (mm >> 1));
  int m0 = m * BM, n0 = n * BN;
  int kEnd = min(2048, m0 + BM);
  const ushort_t* A = Eg + (size_t)bz * (2048 * 2048);
  const ushort_t* B = Vg + (size_t)bz * (1024 * 2048);

  __shared__ ushort_t As[BM * BK];
  __shared__ ushort_t Bs[BN * BK];

  f32x16 acc[2][2];
#pragma unroll
  for (int i = 0; i < 2; ++i)
#pragma unroll
    for (int j = 0; j < 2; ++j)
#pragma unroll
      for (int r = 0; r < 16; ++r) acc[i][j][r] = 0.f;

  gemm_core(A, B, 2048, kEnd, m0, n0, As, Bs, acc);

  int tid = threadIdx.x;
  int lane = tid & 63;
  int wave = tid >> 6;
  int wr = (wave >> 1) * 64;
  int wc = (wave & 1) * 64;
  int l31 = lane & 31;
  int lh = lane >> 5;

  float* C = Og + (size_t)bz * (2048 * 1024);
  const float* rs = rowsum + (size_t)bz * 2048;
#pragma unroll
  for (int fi = 0; fi < 2; ++fi)
#pragma unroll
    for (int r = 0; r < 16; ++r) {
      int rrow = m0 + wr + fi * 32 + (r & 3) + 8 * (r >> 2) + 4 * lh;
      float inv = 1.0f / rs[rrow];
#pragma unroll
      for (int fj = 0; fj < 2; ++fj) {
        int col = n0 + wc + fj * 32 + l31;
        C[(size_t)rrow * 1024 + col] = acc[fi][fj][r] * inv;
      }
    }
}

// ---------------- launch ----------------
extern "C" void kernel_launch(void* const* d_in, const int* in_sizes, int n_in,
                              void* d_out, int out_size, void* d_ws, size_t ws_size,
                              hipStream_t stream) {
  const float* x = (const float*)d_in[0];
  const float* Wq = (const float*)d_in[1];
  const float* Wk = (const float*)d_in[2];
  const float* Wv = (const float*)d_in[3];
  float* out = (float*)d_out;
  char* ws = (char*)d_ws;

  ushort_t* xb = (ushort_t*)(ws);                   // 16 MB
  ushort_t* wqb = (ushort_t*)(ws + (16ull << 20));  // 2 MB
  ushort_t* wkb = (ushort_t*)(ws + (18ull << 20));  // 2 MB
  ushort_t* wvb = (ushort_t*)(ws + (20ull << 20));  // 2 MB
  ushort_t* Qb = (ushort_t*)(ws + (22ull << 20));   // 16 MB
  ushort_t* Kb = (ushort_t*)(ws + (38ull << 20));   // 16 MB
  ushort_t* Vt = (ushort_t*)(ws + (54ull << 20));   // 16 MB (transposed)
  ushort_t* Eb = (ushort_t*)(ws + (70ull << 20));   // 32 MB exp(S) bf16
  float* rowsum = (float*)(ws + (102ull << 20));    // 32 KB fp32

  cast_all_kernel<<<4096 + 3 * 512 + 4, 256, 0, stream>>>(
      x, Wq, Wk, Wv, xb, wqb, wkb, wvb, rowsum);

  // QKV projections, plain grid (measured-best), 1536 = 2 exact rounds
  dim3 gQKV(8192 / BM, 1024 / BN, 3);  // (64, 8, 3)
  gemm_qkv<<<gQKV, 256, 0, stream>>>(xb, wqb, wkb, wvb, Qb, Kb, Vt);

  // S-GEMM, XCD-pinned, single dispatch round (544 = 8 x 68)
  gemm_s<<<dim3(544, 1, 1), 256, 0, stream>>>(Qb, Kb, Eb, 0.03125f, rowsum);

  // O-GEMM, XCD-pinned (512 = 8 x 64), longest-K first, K-balanced
  gemm_o<<<dim3(512, 1, 1), 256, 0, stream>>>(Eb, Vt, out, rowsum);
}